// Round 5
// baseline (414.619 us; speedup 1.0000x reference)
//
#include <hip/hip_runtime.h>

// SelfAttention: B=8, S=2048, D=1024, U=1024, fp32 in/out.
// R5: scores/pv widened to BM=256 x BN=128 tiles (512 thr, 8 waves 4x2) to cut
// per-batch cache re-read traffic (scores 128->96 MB, pv 131->99 MB); inner
// 64x64-per-wave core identical to R4's verified conflict-free 16x16x32 path.
// cast_x + prep_weights fused into one dispatch. qkv unchanged (945 TF in R4).
// Staging: global_load_lds(16B) async + XOR swizzle (slot (row,c8) holds
// global colgroup c8^(row&7)).
// Workspace: 33.6(Xh) + 6.3(WbT) + 33.6*3(QKV) + 67.1(P) = 207.7 MB

#define BK 64

typedef _Float16 half8  __attribute__((ext_vector_type(8)));
typedef _Float16 half4v __attribute__((ext_vector_type(4)));
typedef _Float16 half2v __attribute__((ext_vector_type(2)));
typedef float    floatx4 __attribute__((ext_vector_type(4)));

// ---- async stage: ROWSx64 fp16 tile -> LDS, XOR-swizzled ----
// ITERS*NWAVES*64 lanes cover ROWS*8 16B-chunks; chunk L: row=L>>3, c8=L&7,
// global colgroup cg=c8^(row&7), LDS offset = L*8 halves (wave-uniform base).
template <int ITERS, int NWAVES>
__device__ __forceinline__ void stage_async(const _Float16* __restrict__ src, int ld,
                                            _Float16* __restrict__ dst, int wave, int lane) {
#pragma unroll
    for (int i = 0; i < ITERS; ++i) {
        int chunk = i * NWAVES + wave;
        int L = chunk * 64 + lane;
        int row = L >> 3, c8 = L & 7;
        int cg = c8 ^ (row & 7);
        __builtin_amdgcn_global_load_lds(
            (const __attribute__((address_space(1))) unsigned int*)(src + (size_t)row * ld + cg * 8),
            (__attribute__((address_space(3))) unsigned int*)(dst + chunk * 512),
            16, 0, 0);
    }
}

// ---- one BK=64 K-step: swizzled ds_read_b128 frags + 32 MFMAs (4x4 16x16x32) ----
__device__ __forceinline__ void mfma_accum(const _Float16* __restrict__ As,
                                           const _Float16* __restrict__ Bs,
                                           int wm, int wn, int l15, int q4,
                                           floatx4 acc[4][4]) {
#pragma unroll
    for (int kk = 0; kk < 2; ++kk) {
        half8 a[4], b[4];
#pragma unroll
        for (int i = 0; i < 4; ++i) {
            int row = wm * 64 + i * 16 + l15;
            int cg = (kk * 4 + q4) ^ (row & 7);
            a[i] = *(const half8*)(As + row * 64 + cg * 8);
        }
#pragma unroll
        for (int j = 0; j < 4; ++j) {
            int row = wn * 64 + j * 16 + l15;
            int cg = (kk * 4 + q4) ^ (row & 7);
            b[j] = *(const half8*)(Bs + row * 64 + cg * 8);
        }
#pragma unroll
        for (int i = 0; i < 4; ++i)
#pragma unroll
            for (int j = 0; j < 4; ++j)
                acc[i][j] = __builtin_amdgcn_mfma_f32_16x16x32_f16(a[i], b[j], acc[i][j], 0, 0, 0);
    }
}

// pk-add sum of 8 halves -> float
__device__ __forceinline__ float sum8h(half8 a) {
    union { half8 v; half2v h2[4]; } u; u.v = a;
    half2v s0 = u.h2[0] + u.h2[1];
    half2v s1 = u.h2[2] + u.h2[3];
    half2v s  = s0 + s1;
    return (float)s[0] + (float)s[1];
}

// ---- kernel 0: fused X-cast + weight transpose-cast ----
// bx < 8192: cast 2048 floats of X; else: 32x32 transpose tile of Wq/Wk/Wv.
__global__ void prep_all(const float* __restrict__ X, const float* __restrict__ Wq,
                         const float* __restrict__ Wk, const float* __restrict__ Wv,
                         _Float16* __restrict__ Xh, _Float16* __restrict__ WbT) {
    int bx = blockIdx.x;
    if (bx < 8192) {
        size_t i = ((size_t)bx * 256 + threadIdx.x) * 8;
        float4 v0 = *(const float4*)(X + i);
        float4 v1 = *(const float4*)(X + i + 4);
        half8 hh;
        hh[0] = (_Float16)v0.x; hh[1] = (_Float16)v0.y; hh[2] = (_Float16)v0.z; hh[3] = (_Float16)v0.w;
        hh[4] = (_Float16)v1.x; hh[5] = (_Float16)v1.y; hh[6] = (_Float16)v1.z; hh[7] = (_Float16)v1.w;
        *(half8*)(Xh + i) = hh;
    } else {
        int wb = bx - 8192;                 // 0..3071
        int g = wb >> 10, rem = wb & 1023;
        const float* W = (g == 0) ? Wq : (g == 1) ? Wk : Wv;
        __shared__ float tile[32][33];
        int u0 = (rem & 31) * 32, d0 = (rem >> 5) * 32;
        int tx = threadIdx.x & 31, ty = threadIdx.x >> 5;
#pragma unroll
        for (int i = 0; i < 32; i += 8)
            tile[ty + i][tx] = W[(size_t)(d0 + ty + i) * 1024 + (u0 + tx)];
        __syncthreads();
#pragma unroll
        for (int i = 0; i < 32; i += 8)
            WbT[(size_t)g * 1024 * 1024 + (size_t)(u0 + ty + i) * 1024 + (d0 + tx)] =
                (_Float16)tile[tx][ty + i];
    }
}

// ---- kernel 1: fused QKV projection (128x128, 4 waves — unchanged from R4) ----
__global__ void qkv_gemm(const _Float16* __restrict__ Xh, const _Float16* __restrict__ WbT,
                         _Float16* __restrict__ Qh, _Float16* __restrict__ Kh,
                         _Float16* __restrict__ Vt) {
    __shared__ __align__(16) _Float16 As[128 * BK];
    __shared__ __align__(16) _Float16 Bs[128 * BK];
    int t = threadIdx.x;
    int lane = t & 63, wave = t >> 6;
    int wm = wave >> 1, wn = wave & 1;
    int l15 = lane & 15, q4 = lane >> 4;
    int m0 = blockIdx.y * 128, n0 = blockIdx.x * 128;
    floatx4 acc[4][4] = {};
    for (int kt = 0; kt < 1024; kt += BK) {
        __syncthreads();
        stage_async<4, 4>(Xh + (size_t)m0 * 1024 + kt, 1024, As, wave, lane);
        stage_async<4, 4>(WbT + (size_t)n0 * 1024 + kt, 1024, Bs, wave, lane);
        __syncthreads();
        mfma_accum(As, Bs, wm, wn, l15, q4, acc);
    }
    int which = blockIdx.x >> 3;            // 0=Q 1=K 2=V (block-uniform)
    int u0 = (blockIdx.x & 7) * 128;
    int b = m0 >> 11;
    int sbase = (m0 & 2047) + wm * 64;
    if (which < 2) {
        _Float16* db = (which ? Kh : Qh) + (size_t)b * 2048 * 1024;
#pragma unroll
        for (int i = 0; i < 4; ++i)
#pragma unroll
            for (int j = 0; j < 4; ++j)
#pragma unroll
                for (int r = 0; r < 4; ++r) {
                    int s = sbase + i * 16 + q4 * 4 + r;
                    int u = u0 + wn * 64 + j * 16 + l15;
                    db[(size_t)s * 1024 + u] = (_Float16)acc[i][j][r];
                }
    } else {
        _Float16* vb = Vt + (size_t)b * 1024 * 2048;
#pragma unroll
        for (int i = 0; i < 4; ++i)
#pragma unroll
            for (int j = 0; j < 4; ++j) {
                int s = sbase + i * 16 + q4 * 4;
                int u = u0 + wn * 64 + j * 16 + l15;
                half4v pk;
#pragma unroll
                for (int r = 0; r < 4; ++r) pk[r] = (_Float16)acc[i][j][r];
                *(half4v*)(vb + (size_t)u * 2048 + s) = pk;
            }
    }
}

// ---- kernel 2: scores (256x128 tile, 8 waves), epilogue = exp + store ----
__global__ void __launch_bounds__(512)
scores_gemm(const _Float16* __restrict__ Qh, const _Float16* __restrict__ Kh,
            _Float16* __restrict__ P) {
    __shared__ __align__(16) _Float16 As[256 * BK];   // 32 KB
    __shared__ __align__(16) _Float16 Bs[128 * BK];   // 16 KB
    int t = threadIdx.x;
    int lane = t & 63, wave = t >> 6;                 // 8 waves
    int wm = wave >> 1, wn = wave & 1;                // 4x2
    int l15 = lane & 15, q4 = lane >> 4;
    int m0 = blockIdx.y * 256, n0 = blockIdx.x * 128;
    int batch = blockIdx.z;
    const _Float16* A = Qh + (size_t)batch * 2048 * 1024;
    const _Float16* B = Kh + (size_t)batch * 2048 * 1024;
    floatx4 acc[4][4] = {};
    for (int kt = 0; kt < 1024; kt += BK) {
        __syncthreads();
        stage_async<4, 8>(A + (size_t)m0 * 1024 + kt, 1024, As, wave, lane);
        stage_async<2, 8>(B + (size_t)n0 * 1024 + kt, 1024, Bs, wave, lane);
        __syncthreads();
        mfma_accum(As, Bs, wm, wn, l15, q4, acc);
    }
    _Float16* Pb = P + (size_t)batch * 2048 * 2048;
#pragma unroll
    for (int i = 0; i < 4; ++i)
#pragma unroll
        for (int j = 0; j < 4; ++j)
#pragma unroll
            for (int r = 0; r < 4; ++r) {
                int m = m0 + wm * 64 + i * 16 + q4 * 4 + r;
                int n = n0 + wn * 64 + j * 16 + l15;
                Pb[(size_t)m * 2048 + n] = (_Float16)__expf(acc[i][j][r] * 0.03125f);
            }
}

// ---- kernel 3: P @ V (256x128 tile, 8 waves) with inline rowsum ----
__global__ void __launch_bounds__(512)
pv_gemm(const _Float16* __restrict__ P, const _Float16* __restrict__ Vt,
        float* __restrict__ out) {
    __shared__ __align__(16) _Float16 As[256 * BK];
    __shared__ __align__(16) _Float16 Bs[128 * BK];
    int t = threadIdx.x;
    int lane = t & 63, wave = t >> 6;
    int wm = wave >> 1, wn = wave & 1;
    int l15 = lane & 15, q4 = lane >> 4;
    int m0 = blockIdx.y * 256, n0 = blockIdx.x * 128;
    int batch = blockIdx.z;
    const _Float16* A = P + (size_t)batch * 2048 * 2048;
    const _Float16* B = Vt + (size_t)batch * 1024 * 2048;
    floatx4 acc[4][4] = {};
    float rsum[4] = {0.f, 0.f, 0.f, 0.f};
    for (int kt = 0; kt < 2048; kt += BK) {
        __syncthreads();
        stage_async<4, 8>(A + (size_t)m0 * 2048 + kt, 2048, As, wave, lane);
        stage_async<2, 8>(B + (size_t)n0 * 2048 + kt, 2048, Bs, wave, lane);
        __syncthreads();
#pragma unroll
        for (int kk = 0; kk < 2; ++kk) {
            half8 a[4], b[4];
#pragma unroll
            for (int i = 0; i < 4; ++i) {
                int row = wm * 64 + i * 16 + l15;
                int cg = (kk * 4 + q4) ^ (row & 7);
                a[i] = *(const half8*)(As + row * 64 + cg * 8);
                rsum[i] += sum8h(a[i]);
            }
#pragma unroll
            for (int j = 0; j < 4; ++j) {
                int row = wn * 64 + j * 16 + l15;
                int cg = (kk * 4 + q4) ^ (row & 7);
                b[j] = *(const half8*)(Bs + row * 64 + cg * 8);
            }
#pragma unroll
            for (int i = 0; i < 4; ++i)
#pragma unroll
                for (int j = 0; j < 4; ++j)
                    acc[i][j] = __builtin_amdgcn_mfma_f32_16x16x32_f16(a[i], b[j], acc[i][j], 0, 0, 0);
        }
    }
    // merge q4 k-slices (wave-local; lanes sharing l15 hold same-row partials)
    float rsumf[4];
#pragma unroll
    for (int i = 0; i < 4; ++i) {
        float v = rsum[i] + __shfl_xor(rsum[i], 16);
        rsumf[i] = v + __shfl_xor(v, 32);
    }
    float* ob = out + (size_t)batch * 2048 * 1024;
#pragma unroll
    for (int i = 0; i < 4; ++i)
#pragma unroll
        for (int r = 0; r < 4; ++r) {
            int rloc = q4 * 4 + r;
            float inv = 1.0f / __shfl(rsumf[i], rloc);
            int m = m0 + wm * 64 + i * 16 + rloc;
#pragma unroll
            for (int j = 0; j < 4; ++j) {
                int n = n0 + wn * 64 + j * 16 + l15;
                ob[(size_t)m * 1024 + n] = acc[i][j][r] * inv;
            }
        }
}

extern "C" void kernel_launch(void* const* d_in, const int* in_sizes, int n_in,
                              void* d_out, int out_size, void* d_ws, size_t ws_size,
                              hipStream_t stream) {
    const float* X  = (const float*)d_in[0];
    const float* Wq = (const float*)d_in[1];
    const float* Wk = (const float*)d_in[2];
    const float* Wv = (const float*)d_in[3];
    float* out = (float*)d_out;

    char* ws = (char*)d_ws;
    size_t off = 0;
    _Float16* Xh  = (_Float16*)(ws + off); off += (size_t)8 * 2048 * 1024 * 2;
    _Float16* WbT = (_Float16*)(ws + off); off += (size_t)3 * 1024 * 1024 * 2;
    _Float16* Qh  = (_Float16*)(ws + off); off += (size_t)8 * 2048 * 1024 * 2;
    _Float16* Kh  = (_Float16*)(ws + off); off += (size_t)8 * 2048 * 1024 * 2;
    _Float16* Vt  = (_Float16*)(ws + off); off += (size_t)8 * 1024 * 2048 * 2;
    _Float16* P   = (_Float16*)(ws + off); off += (size_t)8 * 2048 * 2048 * 2;

    prep_all   <<<dim3(11264, 1, 1), 256, 0, stream>>>(X, Wq, Wk, Wv, Xh, WbT);
    qkv_gemm   <<<dim3(24, 128, 1), 256, 0, stream>>>(Xh, WbT, Qh, Kh, Vt);
    scores_gemm<<<dim3(16, 8, 8),  512, 0, stream>>>(Qh, Kh, P);
    pv_gemm    <<<dim3(8, 8, 8),   512, 0, stream>>>(P, Vt, out);
}